// Round 11
// baseline (110.297 us; speedup 1.0000x reference)
//
#include <hip/hip_runtime.h>
#include <hip/hip_bf16.h>

typedef unsigned short ushort_t;
typedef unsigned int u32;
typedef unsigned long long u64;
typedef __attribute__((ext_vector_type(8))) short bf16x8;
typedef __attribute__((ext_vector_type(4))) float f32x4;
typedef __attribute__((ext_vector_type(4))) u32 u32x4;

#define NB 128
#define PP 200
#define KK 60
#define NN (NB*PP)      // 25600
#define HH 64

// d_out is FLOAT32. Offsets in f32 elements: out, pos, batch, edge(src,dst)
#define OUT_OFF   0
#define POS_OFF   (NN*HH)             // 1638400
#define BATCH_OFF (POS_OFF + NN*3)    // 1715200
#define ESRC_OFF  (BATCH_OFF + NN)    // 1740800
#define EDST_OFF  (ESRC_OFF + NN*KK)  // 3276800

// truncating bf16x2 pack in ONE v_perm_b32: D = (hi16 of b)<<16 | (hi16 of a)
static __device__ __forceinline__ u32 packtr(float a, float b) {
    return __builtin_amdgcn_perm(__float_as_uint(b), __float_as_uint(a), 0x07060302u);
}
static __device__ __forceinline__ u32 prefix_lt(u64 b) {   // #set bits below lane
    return __builtin_amdgcn_mbcnt_hi((u32)(b >> 32),
                                     __builtin_amdgcn_mbcnt_lo((u32)b, 0));
}

// ---------------------------------------------------------------------------
// FUSED kernel, round 11: block = 128 threads (2 waves), 4 targets (2/wave),
// grid 6400 -> 16 blocks/CU (full 32-wave cap), smooth tail.
// Phase B: interleaved early-exit wave-ballot binary searches (exact top-60
//   set; slot order free under the absmax threshold), ballot+mbcnt compaction.
// Phase C: CHANNEL-PERMUTED layer 1: W1 columns loaded in order
//   c(m) = 32*(th>>1) + 8*((m>>2)&3) + 4*(th&1) + (m&3), which makes the
//   MFMA C-fragment of layer 1 coincide bit-for-bit with layer 2's
//   A-fragment layout => the af LDS round-trip is replaced by register
//   recombination. W2/b2 stay unpermuted (channel c sits at k'=c).
//   No zero-row select: w1f has A[k>=8]=0, so msg garbage at k>=8 is harmless.
// ---------------------------------------------------------------------------
__global__ __launch_bounds__(128) void fused_kernel(const float* __restrict__ x,
                                                    const float* __restrict__ pos,
                                                    const float* __restrict__ W1,
                                                    const float* __restrict__ b1p,
                                                    const float* __restrict__ W2,
                                                    const float* __restrict__ b2p,
                                                    float* __restrict__ out) {
    __shared__ alignas(16) float xs[PP * 4];     // 3200 B
    __shared__ alignas(16) float psl[PP * 3];    // 2400 B
    __shared__ alignas(16) u32 jslot[2 * 128];   // 1024 B
    __shared__ alignas(16) u32 msg[2 * 256];     // 2048 B

    int tid = threadIdx.x, blk = blockIdx.x;
    int e = blk / 50;
    int pl0b = (blk % 50) * 4;      // first local target of this block
    int i0b  = e * PP + pl0b;

    ((f32x4*)xs)[tid] = ((const f32x4*)x)[e * PP + tid];
    if (tid < 72)  ((f32x4*)xs)[128 + tid]  = ((const f32x4*)x)[e * PP + 128 + tid];
    if (tid < 128) ((f32x4*)psl)[tid]       = ((const f32x4*)pos)[e * 150 + tid];
    if (tid < 22)  ((f32x4*)psl)[128 + tid] = ((const f32x4*)pos)[e * 150 + 128 + tid];
    __syncthreads();

    if (tid < 12) out[POS_OFF + i0b * 3 + tid] = psl[pl0b * 3 + tid];
    if (tid < 4)  out[BATCH_OFF + i0b + tid] = (float)e;

    int lane = tid & 63, wv = tid >> 6;
    int lo16 = lane & 15, hi16 = lane >> 4;
    int plA = pl0b + wv * 2, plB = plA + 1;
    int iA = e * PP + plA,   iB = iA + 1;

    // ---------------- Phase B: KNN for two targets ----------------
    float axA = psl[plA*3], ayA = psl[plA*3+1], azA = psl[plA*3+2];
    float axB = psl[plB*3], ayB = psl[plB*3+1], azB = psl[plB*3+2];

    u32 keyA[4], keyB[4];
    #pragma unroll
    for (int q = 0; q < 4; ++q) {
        int j = lane + q * 64;
        int jc = (j < PP) ? j : 0;
        float px = psl[jc*3], py = psl[jc*3+1], pz = psl[jc*3+2];
        float dxA = px-axA, dyA = py-ayA, dzA = pz-azA;
        float dxB = px-axB, dyB = py-ayB, dzB = pz-azB;
        float d2A = dxA*dxA + dyA*dyA + dzA*dzA;
        float d2B = dxB*dxB + dyB*dyB + dzB*dzB;
        keyA[q] = (j < PP && j != plA)
                ? ((__float_as_uint(d2A) & 0xFFFFFF00u) | (u32)j) : 0xFFFFFFFFu;
        keyB[q] = (j < PP && j != plB)
                ? ((__float_as_uint(d2B) & 0xFFFFFF00u) | (u32)j) : 0xFFFFFFFFu;
    }

    // interleaved early-exit binary searches for the exact-60 threshold
    u32 loA = 0u, hiA = 0x7F800000u, loB = 0u, hiB = 0x7F800000u;
    int doneA = 0, doneB = 0;
    for (int it = 0; it < 32; ++it) {
        u32 mA = loA + ((hiA - loA) >> 1);
        u32 mB = loB + ((hiB - loB) >> 1);
        int cA = __builtin_popcountll(__ballot(keyA[0] < mA))
               + __builtin_popcountll(__ballot(keyA[1] < mA))
               + __builtin_popcountll(__ballot(keyA[2] < mA))
               + __builtin_popcountll(__ballot(keyA[3] < mA));
        int cB = __builtin_popcountll(__ballot(keyB[0] < mB))
               + __builtin_popcountll(__ballot(keyB[1] < mB))
               + __builtin_popcountll(__ballot(keyB[2] < mB))
               + __builtin_popcountll(__ballot(keyB[3] < mB));
        if (!doneA) {
            if (cA >= KK) hiA = mA; else loA = mA;
            doneA = (cA == KK) | (hiA - loA <= 1u);
        }
        if (!doneB) {
            if (cB >= KK) hiB = mB; else loB = mB;
            doneB = (cB == KK) | (hiB - loB <= 1u);
        }
        if (doneA & doneB) break;
    }

    const int jsb = wv * 128;
    if (lane >= KK) {                            // slots 60..63 = self id
        jslot[jsb + lane]      = (u32)plA;
        jslot[jsb + 64 + lane] = (u32)plB;
    }
    #pragma unroll
    for (int t = 0; t < 2; ++t) {
        const u32* key = t ? keyB : keyA;
        u32 hh = t ? hiB : hiA;
        int i  = t ? iB : iA;
        u64 m0 = __ballot(key[0] < hh);
        u64 m1 = __ballot(key[1] < hh);
        u64 m2 = __ballot(key[2] < hh);
        u64 m3 = __ballot(key[3] < hh);
        u32 s1 = (u32)__builtin_popcountll(m0);
        u32 s2 = s1 + (u32)__builtin_popcountll(m1);
        u32 s3 = s2 + (u32)__builtin_popcountll(m2);
        u32 sl[4] = { prefix_lt(m0), s1 + prefix_lt(m1),
                      s2 + prefix_lt(m2), s3 + prefix_lt(m3) };
        #pragma unroll
        for (int q = 0; q < 4; ++q) {
            if (key[q] < hh) {
                u32 j = key[q] & 0xFFu;
                out[ESRC_OFF + i * KK + (int)sl[q]] = (float)(e * PP + (int)j);
                jslot[jsb + t * 64 + (int)sl[q]] = j;
            }
        }
        if (lane < KK) out[EDST_OFF + i * KK + lane] = (float)i;
    }

    // ------------- weights (channel-permuted W1', plain W2) -------------
    bf16x8 w1f[4];
    #pragma unroll
    for (int th = 0; th < 4; ++th) {
        union { u32 w[4]; bf16x8 v; } u; u.w[0]=u.w[1]=u.w[2]=u.w[3]=0u;
        if (hi16 == 0) {
            int c = 32*(th>>1) + 8*(lo16>>2) + 4*(th&1) + (lo16&3);
            u.w[0] = packtr(W1[0*64+c], W1[1*64+c]);
            u.w[1] = packtr(W1[2*64+c], W1[3*64+c]);
            u.w[2] = packtr(W1[4*64+c], W1[5*64+c]);
            u.w[3] = packtr(W1[6*64+c], b1p[c]);     // bias in slot 7
        }
        w1f[th] = u.v;
    }
    bf16x8 bfr[4][2];
    #pragma unroll
    for (int t = 0; t < 4; ++t)
        #pragma unroll
        for (int s = 0; s < 2; ++s) {
            union { u32 w[4]; bf16x8 v; } u;
            int col = t * 16 + lo16, kb = s * 32 + hi16 * 8;
            #pragma unroll
            for (int d = 0; d < 4; ++d)
                u.w[d] = packtr(W2[(kb + 2*d) * 64 + col], W2[(kb + 2*d + 1) * 64 + col]);
            bfr[t][s] = u.v;
        }
    float b2v[4];
    #pragma unroll
    for (int t = 0; t < 4; ++t) b2v[t] = b2p[t * 16 + lo16];

    // ---------------- Phase C: MLP + max-aggregate ----------------
    const int msb = wv * 256;
    for (int tl = 0; tl < 2; ++tl) {
        int i = iA + tl, pl = plA + tl;
        int jloc = (int)jslot[jsb + tl * 64 + lane];
        f32x4 xv = ((const f32x4*)xs)[jloc];
        float rx = psl[jloc*3]   - psl[pl*3];
        float ry = psl[jloc*3+1] - psl[pl*3+1];
        float rz = psl[jloc*3+2] - psl[pl*3+2];
        u32x4 mrow;
        mrow[0] = packtr(xv[0], xv[1]);
        mrow[1] = packtr(xv[2], xv[3]);
        mrow[2] = packtr(rx, ry);
        mrow[3] = packtr(rz, 1.0f);
        *(u32x4*)&msg[msb + lane * 4] = mrow;

        float rmax[4] = {-3.0e38f, -3.0e38f, -3.0e38f, -3.0e38f};
        #pragma unroll
        for (int rt = 0; rt < 4; ++rt) {
            // B-frag: every lane reads row rt*16+lo16 (broadcast across hi16;
            // k>=8 lanes feed zeros in A, so their finite values are harmless)
            union { u32 w[4]; bf16x8 v; } mu;
            *(u32x4*)mu.w = *(const u32x4*)&msg[msb + (rt * 16 + lo16) * 4];

            f32x4 c1[4];
            #pragma unroll
            for (int th = 0; th < 4; ++th)
                c1[th] = __builtin_amdgcn_mfma_f32_16x16x32_bf16(w1f[th], mu.v,
                                                                 (f32x4)0.f, 0, 0, 0);
            // relu + pack: C-frag of permuted layer 1 == layer-2 A-frag
            union { u32 w[4]; bf16x8 v; } afr[2];
            #pragma unroll
            for (int th = 0; th < 4; ++th) {
                u32 pk0 = packtr(fmaxf(c1[th][0], 0.f), fmaxf(c1[th][1], 0.f));
                u32 pk1 = packtr(fmaxf(c1[th][2], 0.f), fmaxf(c1[th][3], 0.f));
                afr[th >> 1].w[2 * (th & 1) + 0] = pk0;
                afr[th >> 1].w[2 * (th & 1) + 1] = pk1;
            }
            f32x4 acc[4];
            #pragma unroll
            for (int t = 0; t < 4; ++t)
                acc[t] = __builtin_amdgcn_mfma_f32_16x16x32_bf16(afr[0].v, bfr[t][0],
                                                                 (f32x4)0.f, 0, 0, 0);
            #pragma unroll
            for (int t = 0; t < 4; ++t)
                acc[t] = __builtin_amdgcn_mfma_f32_16x16x32_bf16(afr[1].v, bfr[t][1],
                                                                 acc[t], 0, 0, 0);
            // raw-acc max; +b2 and relu commute past the row-max
            #pragma unroll
            for (int t = 0; t < 4; ++t) {
                rmax[t] = fmaxf(fmaxf(acc[t][0], acc[t][1]), rmax[t]);
                rmax[t] = fmaxf(fmaxf(acc[t][2], acc[t][3]), rmax[t]);
            }
        }
        #pragma unroll
        for (int t = 0; t < 4; ++t) {
            rmax[t] = fmaxf(rmax[t], __shfl_xor(rmax[t], 16, 64));
            rmax[t] = fmaxf(rmax[t], __shfl_xor(rmax[t], 32, 64));
        }
        if (lane < 16) {
            #pragma unroll
            for (int t = 0; t < 4; ++t)
                out[OUT_OFF + i * 64 + t * 16 + lane] = fmaxf(rmax[t] + b2v[t], 0.f);
        }
    }
}

// ---------------------------------------------------------------------------
extern "C" void kernel_launch(void* const* d_in, const int* in_sizes, int n_in,
                              void* d_out, int out_size, void* d_ws, size_t ws_size,
                              hipStream_t stream) {
    const float* x     = (const float*)d_in[0];
    const float* pos   = (const float*)d_in[1];
    const float* W1    = (const float*)d_in[3];
    const float* b1    = (const float*)d_in[4];
    const float* W2    = (const float*)d_in[5];
    const float* b2    = (const float*)d_in[6];
    float* out = (float*)d_out;
    (void)d_ws; (void)ws_size; (void)in_sizes; (void)n_in; (void)out_size;

    fused_kernel<<<dim3(NN / 4), dim3(128), 0, stream>>>(x, pos, W1, b1, W2, b2, out);
}